// Round 17
// baseline (1825.413 us; speedup 1.0000x reference)
//
#include <hip/hip_runtime.h>
#include <cstdint>
#include <cstddef>

#define TT 1024
#define BB 256
#define II 128
#define HH 256
#define GG 768
#define OO 64
#define TCH 64             // timesteps per chunk (16 chunks; enables xg dbuf)
#define NCH (TT / TCH)

typedef float f32x4 __attribute__((ext_vector_type(4)));
typedef short short8 __attribute__((ext_vector_type(8)));

__device__ __forceinline__ unsigned f2bf(float f) {
  unsigned u = __builtin_bit_cast(unsigned, f);
  return (u + 0x7FFFu + ((u >> 16) & 1u)) >> 16;   // RNE
}
__device__ __forceinline__ float bflo(unsigned p) {   // low bf16 -> f32
  return __builtin_bit_cast(float, p << 16);
}
__device__ __forceinline__ float bfhi(unsigned p) {   // high bf16 -> f32
  return __builtin_bit_cast(float, p & 0xffff0000u);
}
__device__ __forceinline__ unsigned cvtpk_bf16(float lo, float hi) {
  unsigned r;
  asm("v_cvt_pk_bf16_f32 %0, %1, %2" : "=v"(r) : "v"(lo), "v"(hi));
  return r;
}
__device__ __forceinline__ float sigm(float x) {
  return __builtin_amdgcn_rcpf(1.f + __builtin_amdgcn_exp2f(-1.44269504088896f * x));
}

// ---------------- b_total: b_ih + (b_hh for r,z gates only) ----------------
__global__ void k_btot(const float* __restrict__ bih, const float* __restrict__ bhh,
                       float* __restrict__ btot) {
  int i = blockIdx.x * 256 + threadIdx.x;
  if (i < GG) btot[i] = bih[i] + (i < 512 ? bhh[i] : 0.f);
}

// ---------------- standalone xg for chunk 0 (proven R7-R16, 512 thr) --------
// Record: idx = ((tl*16 + mt)*48 + ut)*64 + lane; uint2 = packed bf16 of the
// 4 pre-acts for units ut*16 + quad*4 + {0..3}, batch row mt*16 + cu.
__global__ __attribute__((amdgpu_flat_work_group_size(512, 512), amdgpu_waves_per_eu(2, 2)))
void k_xg(const float* __restrict__ x,
    const float* __restrict__ Wih, const float* __restrict__ btot,
    unsigned short* __restrict__ xg, int t0)
{
  __shared__ unsigned short xlds[BB * II];   // 64KB, swizzled bf16 of x[:, t, :]
  const int tid = threadIdx.x;
  const int tl = blockIdx.x;
  const int tg = t0 + tl;
  const int w = tid >> 6, lane = tid & 63, cu = lane & 15, quad = lane >> 4;

  for (int i = 0; i < 16; ++i) {
    int cid = tid + i * 512;          // 8192 16B-chunks (256 rows x 32)
    int row = cid >> 5, c16 = cid & 31;
    const float4 v = *(const float4*)(x + (size_t)row * TT * II + (size_t)tg * II + c16 * 4);
    unsigned lo = f2bf(v.x) | (f2bf(v.y) << 16);
    unsigned hi = f2bf(v.z) | (f2bf(v.w) << 16);
    int byt = (row * 256 + c16 * 8) ^ ((row & 7) << 4);
    *(uint2*)((char*)xlds + byt) = make_uint2(lo, hi);
  }

  uint4 WA[3][2][4];
  float bias[3][2][4];
  #pragma unroll
  for (int pp = 0; pp < 3; ++pp)
    #pragma unroll
    for (int t2 = 0; t2 < 2; ++t2) {
      int ut = w * 6 + pp * 2 + t2;
      int grow = ut * 16 + cu;
      const float4* wr = (const float4*)(Wih + (size_t)grow * II);
      #pragma unroll
      for (int kk = 0; kk < 4; ++kk) {
        float4 lo = wr[kk * 8 + quad * 2];
        float4 hi = wr[kk * 8 + quad * 2 + 1];
        uint4 pk;
        pk.x = f2bf(lo.x) | (f2bf(lo.y) << 16);
        pk.y = f2bf(lo.z) | (f2bf(lo.w) << 16);
        pk.z = f2bf(hi.x) | (f2bf(hi.y) << 16);
        pk.w = f2bf(hi.z) | (f2bf(hi.w) << 16);
        WA[pp][t2][kk] = pk;
      }
      #pragma unroll
      for (int j = 0; j < 4; ++j)
        bias[pp][t2][j] = btot[ut * 16 + quad * 4 + j];
    }
  __syncthreads();

  #pragma unroll 1
  for (int mt = 0; mt < 16; ++mt) {
    short8 bf[4];
    int brow = mt * 16 + cu;
    #pragma unroll
    for (int kk = 0; kk < 4; ++kk) {
      int byt = (brow * 256 + kk * 64 + quad * 16) ^ ((cu & 7) << 4);
      bf[kk] = *(const short8*)((const char*)xlds + byt);
    }
    f32x4 acc[3][2];
    #pragma unroll
    for (int pp = 0; pp < 3; ++pp) {
      acc[pp][0] = (f32x4){0.f, 0.f, 0.f, 0.f};
      acc[pp][1] = (f32x4){0.f, 0.f, 0.f, 0.f};
    }
    #pragma unroll
    for (int kk = 0; kk < 4; ++kk)
      #pragma unroll
      for (int pp = 0; pp < 3; ++pp)
        #pragma unroll
        for (int t2 = 0; t2 < 2; ++t2)
          acc[pp][t2] = __builtin_amdgcn_mfma_f32_16x16x32_bf16(
              __builtin_bit_cast(short8, WA[pp][t2][kk]), bf[kk], acc[pp][t2], 0, 0, 0);
    #pragma unroll
    for (int pp = 0; pp < 3; ++pp)
      #pragma unroll
      for (int t2 = 0; t2 < 2; ++t2) {
        int ut = w * 6 + pp * 2 + t2;
        unsigned p0 = cvtpk_bf16(acc[pp][t2][0] + bias[pp][t2][0],
                                 acc[pp][t2][1] + bias[pp][t2][1]);
        unsigned p1 = cvtpk_bf16(acc[pp][t2][2] + bias[pp][t2][2],
                                 acc[pp][t2][3] + bias[pp][t2][3]);
        size_t rec = ((size_t)(tl * 16 + mt) * 48 + ut) * 64 + lane;
        ((uint2*)xg)[rec] = make_uint2(p0, p1);
      }
  }
}

// ---------------- fused dispatch: scan(chunk c) || xg(chunk c+1) ------------
// WGs 0-15: the R16 scan body verbatim (16 waves x 16 units, W kk0-6 in regs,
// kk7 in wlds, h double-buffered in hbuf, reads xg_rd).
// WGs 16+: one timestep of xg for the NEXT chunk on otherwise-idle CUs,
// writing xg_wr (disjoint buffer -> no intra-dispatch dependency). xlds is
// aliased onto hbuf (both 64KB).
__global__ __launch_bounds__(1024, 4) void k_fused(const float* __restrict__ Whh,
    const float* __restrict__ bhh, const float* __restrict__ alpha,
    const unsigned short* __restrict__ xg_rd, float* __restrict__ hlast, int t0,
    const float* __restrict__ x, const float* __restrict__ Wih,
    const float* __restrict__ btot, unsigned short* __restrict__ xg_wr)
{
  __shared__ unsigned short hbuf[2][16384];     // 64KB (scan h dbuf / xg xlds)
  __shared__ uint4 wlds[16][3][64];             // 48KB: W_hh kk=7 fragments
  const int tid = threadIdx.x, wv = tid >> 6, lane = tid & 63;
  const int cu = lane & 15, quad = lane >> 4;
  const int wg = blockIdx.x;

  if (wg >= 16) {
    // ================= xg body (next chunk), timestep tl = wg-16 ===========
    unsigned short* xlds = (unsigned short*)hbuf;  // 64KB alias
    const int tl = wg - 16;
    const int tg = t0 + TCH + tl;

    for (int i = 0; i < 8; ++i) {
      int cid = tid + i * 1024;       // 8192 16B-chunks (256 rows x 32)
      int row = cid >> 5, c16 = cid & 31;
      const float4 v = *(const float4*)(x + (size_t)row * TT * II + (size_t)tg * II + c16 * 4);
      unsigned lo = f2bf(v.x) | (f2bf(v.y) << 16);
      unsigned hi = f2bf(v.z) | (f2bf(v.w) << 16);
      int byt = (row * 256 + c16 * 8) ^ ((row & 7) << 4);
      *(uint2*)((char*)xlds + byt) = make_uint2(lo, hi);
    }

    uint4 WA[3][2][4];
    float bias[3][2][4];
    const int w = tid >> 6;           // only waves 0-7 compute
    if (tid < 512) {
      #pragma unroll
      for (int pp = 0; pp < 3; ++pp)
        #pragma unroll
        for (int t2 = 0; t2 < 2; ++t2) {
          int ut = w * 6 + pp * 2 + t2;
          int grow = ut * 16 + cu;
          const float4* wr = (const float4*)(Wih + (size_t)grow * II);
          #pragma unroll
          for (int kk = 0; kk < 4; ++kk) {
            float4 lo = wr[kk * 8 + quad * 2];
            float4 hi = wr[kk * 8 + quad * 2 + 1];
            uint4 pk;
            pk.x = f2bf(lo.x) | (f2bf(lo.y) << 16);
            pk.y = f2bf(lo.z) | (f2bf(lo.w) << 16);
            pk.z = f2bf(hi.x) | (f2bf(hi.y) << 16);
            pk.w = f2bf(hi.z) | (f2bf(hi.w) << 16);
            WA[pp][t2][kk] = pk;
          }
          #pragma unroll
          for (int j = 0; j < 4; ++j)
            bias[pp][t2][j] = btot[ut * 16 + quad * 4 + j];
        }
    }
    __syncthreads();
    if (tid >= 512) return;

    #pragma unroll 1
    for (int mt = 0; mt < 16; ++mt) {
      short8 bf[4];
      int brow = mt * 16 + cu;
      #pragma unroll
      for (int kk = 0; kk < 4; ++kk) {
        int byt = (brow * 256 + kk * 64 + quad * 16) ^ ((cu & 7) << 4);
        bf[kk] = *(const short8*)((const char*)xlds + byt);
      }
      f32x4 acc[3][2];
      #pragma unroll
      for (int pp = 0; pp < 3; ++pp) {
        acc[pp][0] = (f32x4){0.f, 0.f, 0.f, 0.f};
        acc[pp][1] = (f32x4){0.f, 0.f, 0.f, 0.f};
      }
      #pragma unroll
      for (int kk = 0; kk < 4; ++kk)
        #pragma unroll
        for (int pp = 0; pp < 3; ++pp)
          #pragma unroll
          for (int t2 = 0; t2 < 2; ++t2)
            acc[pp][t2] = __builtin_amdgcn_mfma_f32_16x16x32_bf16(
                __builtin_bit_cast(short8, WA[pp][t2][kk]), bf[kk], acc[pp][t2], 0, 0, 0);
      #pragma unroll
      for (int pp = 0; pp < 3; ++pp)
        #pragma unroll
        for (int t2 = 0; t2 < 2; ++t2) {
          int ut = w * 6 + pp * 2 + t2;
          unsigned p0 = cvtpk_bf16(acc[pp][t2][0] + bias[pp][t2][0],
                                   acc[pp][t2][1] + bias[pp][t2][1]);
          unsigned p1 = cvtpk_bf16(acc[pp][t2][2] + bias[pp][t2][2],
                                   acc[pp][t2][3] + bias[pp][t2][3]);
          size_t rec = ((size_t)(tl * 16 + mt) * 48 + ut) * 64 + lane;
          ((uint2*)xg_wr)[rec] = make_uint2(p0, p1);
        }
    }
    return;
  }

  // ================= scan body (R16 verbatim, TCH=64) =======================
  uint4 Wf[3][7];
  #pragma unroll
  for (int g = 0; g < 3; ++g) {
    int grow = g * 256 + wv * 16 + cu;
    const float4* wr = (const float4*)(Whh + (size_t)grow * HH);
    #pragma unroll
    for (int kk = 0; kk < 8; ++kk) {
      float4 lo = wr[kk * 8 + quad * 2];
      float4 hi = wr[kk * 8 + quad * 2 + 1];
      uint4 pk;
      pk.x = cvtpk_bf16(lo.x, lo.y);
      pk.y = cvtpk_bf16(lo.z, lo.w);
      pk.z = cvtpk_bf16(hi.x, hi.y);
      pk.w = cvtpk_bf16(hi.z, hi.w);
      if (kk < 7) Wf[g][kk] = pk;
      else        wlds[wv][g][lane] = pk;
    }
  }
  const int u0 = wv * 16 + quad * 4;
  unsigned asigp[2], bhp[2];
  asigp[0] = cvtpk_bf16(sigm(alpha[u0]),     sigm(alpha[u0 + 1]));
  asigp[1] = cvtpk_bf16(sigm(alpha[u0 + 2]), sigm(alpha[u0 + 3]));
  bhp[0] = f2bf(bhh[512 + u0])     | (f2bf(bhh[512 + u0 + 1]) << 16);
  bhp[1] = f2bf(bhh[512 + u0 + 2]) | (f2bf(bhh[512 + u0 + 3]) << 16);

  for (int i = 0; i < 4; ++i) {
    int idx = tid * 4 + i;            // 4096 = 16 rows x 256 units
    int m = idx >> 8, u = idx & 255;
    float hv = (t0 == 0) ? 0.f : hlast[((size_t)wg * 16 + m) * 256 + u];
    int byt = (m * 512 + u * 2) ^ ((m & 7) << 4) ^ ((m >> 3) << 6);
    *(unsigned short*)((char*)hbuf[0] + byt) = (unsigned short)f2bf(hv);
  }
  __syncthreads();

  const unsigned swz = (unsigned)(((cu & 7) << 4) ^ ((cu >> 3) << 6));
  const unsigned vb  = (unsigned)((cu * 512 + quad * 16)) ^ swz;
  const unsigned whp = (unsigned)((cu * 512 + wv * 32 + quad * 8)) ^ swz;

  const uint2* xq = (const uint2*)xg_rd + ((size_t)wg * 48 + wv) * 64 + lane;
  uint2 qn0 = xq[0], qn1 = xq[1024], qn2 = xq[2048];

  unsigned bufb = 0;
  const char* hbase = (const char*)hbuf;

  for (int tl = 0; tl < TCH; ++tl) {
    const char* hs = hbase + bufb;
    f32x4 acc[3];
    acc[0][0]=bflo(qn0.x); acc[0][1]=bfhi(qn0.x); acc[0][2]=bflo(qn0.y); acc[0][3]=bfhi(qn0.y);
    acc[1][0]=bflo(qn1.x); acc[1][1]=bfhi(qn1.x); acc[1][2]=bflo(qn1.y); acc[1][3]=bfhi(qn1.y);
    acc[2][0]=bflo(bhp[0]); acc[2][1]=bfhi(bhp[0]);
    acc[2][2]=bflo(bhp[1]); acc[2][3]=bfhi(bhp[1]);
    uint2 q2c = qn2;
    if (tl < TCH - 1) xq += 49152;
    qn0 = xq[0]; qn1 = xq[1024]; qn2 = xq[2048];
    uint2 hpq = *(const uint2*)(hs + whp);

    #pragma unroll
    for (int kk = 0; kk < 7; ++kk) {
      short8 bfh = *(const short8*)(hs + (vb ^ (unsigned)(kk * 64)));
      #pragma unroll
      for (int g = 0; g < 3; ++g)
        acc[g] = __builtin_amdgcn_mfma_f32_16x16x32_bf16(
            __builtin_bit_cast(short8, Wf[g][kk]), bfh, acc[g], 0, 0, 0);
    }
    {
      short8 bfh = *(const short8*)(hs + (vb ^ (unsigned)(7 * 64)));
      #pragma unroll
      for (int g = 0; g < 3; ++g) {
        short8 wf = __builtin_bit_cast(short8, wlds[wv][g][lane]);
        acc[g] = __builtin_amdgcn_mfma_f32_16x16x32_bf16(wf, bfh, acc[g], 0, 0, 0);
      }
    }

    float hpv[4] = {bflo(hpq.x), bfhi(hpq.x), bflo(hpq.y), bfhi(hpq.y)};
    float xgn[4] = {bflo(q2c.x), bfhi(q2c.x), bflo(q2c.y), bfhi(q2c.y)};
    float av[4]  = {bflo(asigp[0]), bfhi(asigp[0]), bflo(asigp[1]), bfhi(asigp[1])};
    float ho[4];
    #pragma unroll
    for (int j = 0; j < 4; ++j) {
      float rr = sigm(acc[0][j]);                        // r-gate
      float ss = sigm(-acc[1][j]);                       // 1 - z
      float v  = fmaf(rr, acc[2][j], xgn[j]);
      float nn = 1.f - 2.f * __builtin_amdgcn_rcpf(
                     1.f + __builtin_amdgcn_exp2f(2.88539008177793f * v));
      ho[j] = fmaf(av[j] * ss, nn - hpv[j], hpv[j]);
    }
    unsigned p0 = cvtpk_bf16(ho[0], ho[1]);
    unsigned p1 = cvtpk_bf16(ho[2], ho[3]);
    *(uint2*)((char*)hbase + (bufb ^ 32768u) + whp) = make_uint2(p0, p1);
    if (tl == TCH - 1) {
      #pragma unroll
      for (int j = 0; j < 4; ++j)
        hlast[((size_t)wg * 16 + cu) * 256 + u0 + j] = ho[j];
    }
    __syncthreads();
    bufb ^= 32768u;
  }
}

// ---------------- phase 3: out = sigmoid(h_last @ fc_w^T + fc_b) ------------
__global__ void k_out(const float* __restrict__ hlast, const float* __restrict__ fcw,
                      const float* __restrict__ fcb, float* __restrict__ out)
{
  int g = blockIdx.x * 256 + threadIdx.x;   // 16384 outputs
  int b = g >> 6, o = g & 63;
  const float* hr = hlast + (size_t)b * HH;
  const float* wr = fcw + (size_t)o * HH;
  float acc = fcb[o];
  for (int u = 0; u < HH; ++u) acc = fmaf(hr[u], wr[u], acc);
  out[g] = sigm(acc);
}

extern "C" void kernel_launch(void* const* d_in, const int* in_sizes, int n_in,
                              void* d_out, int out_size, void* d_ws, size_t ws_size,
                              hipStream_t stream)
{
  const float* x   = (const float*)d_in[0];
  const float* Wih = (const float*)d_in[1];
  const float* Whh = (const float*)d_in[2];
  const float* bih = (const float*)d_in[3];
  const float* bhh = (const float*)d_in[4];
  const float* alp = (const float*)d_in[5];
  const float* fcw = (const float*)d_in[6];
  const float* fcb = (const float*)d_in[7];
  float* out = (float*)d_out;

  const size_t XGB1 = (size_t)TCH * 16 * 48 * 64 * 8;  // 25,165,824 B per buffer
  const size_t HLB  = (size_t)BB * HH * 4;             // 262,144 B
  const size_t BTB  = (size_t)GG * 4;                  // 3,072 B
  if (ws_size < 2 * XGB1 + HLB + BTB) return;          // ~50.6 MB scratch

  unsigned short* xgA = (unsigned short*)d_ws;
  unsigned short* xgB = (unsigned short*)((char*)d_ws + XGB1);
  float* hlast = (float*)((char*)d_ws + 2 * XGB1);
  float* btot  = (float*)((char*)d_ws + 2 * XGB1 + HLB);

  k_btot<<<3, 256, 0, stream>>>(bih, bhh, btot);
  k_xg<<<TCH, 512, 0, stream>>>(x, Wih, btot, xgA, 0);
  for (int c = 0; c < NCH; ++c) {
    unsigned short* rd = (c & 1) ? xgB : xgA;
    unsigned short* wr = (c & 1) ? xgA : xgB;
    int nxg = (c + 1 < NCH) ? TCH : 0;
    k_fused<<<16 + nxg, 1024, 0, stream>>>(Whh, bhh, alp, rd, hlast, c * TCH,
                                           x, Wih, btot, wr);
  }
  k_out<<<64, 256, 0, stream>>>(hlast, fcw, fcb, out);
}

// Round 18
// 1641.154 us; speedup vs baseline: 1.1123x; 1.1123x over previous
//
#include <hip/hip_runtime.h>
#include <cstdint>
#include <cstddef>

#define TT 1024
#define BB 256
#define II 128
#define HH 256
#define GG 768
#define OO 64
#define TCH 256            // timesteps per chunk
#define NCH (TT / TCH)

typedef float f32x4 __attribute__((ext_vector_type(4)));
typedef short short8 __attribute__((ext_vector_type(8)));

__device__ __forceinline__ unsigned f2bf(float f) {
  unsigned u = __builtin_bit_cast(unsigned, f);
  return (u + 0x7FFFu + ((u >> 16) & 1u)) >> 16;   // RNE
}
__device__ __forceinline__ float bflo(unsigned p) {   // low bf16 -> f32
  return __builtin_bit_cast(float, p << 16);
}
__device__ __forceinline__ float bfhi(unsigned p) {   // high bf16 -> f32
  return __builtin_bit_cast(float, p & 0xffff0000u);
}
__device__ __forceinline__ unsigned cvtpk_bf16(float lo, float hi) {
  unsigned r;
  asm("v_cvt_pk_bf16_f32 %0, %1, %2" : "=v"(r) : "v"(lo), "v"(hi));
  return r;
}
__device__ __forceinline__ float sigm(float x) {
  return __builtin_amdgcn_rcpf(1.f + __builtin_amdgcn_exp2f(-1.44269504088896f * x));
}

// ---------------- b_total: b_ih + (b_hh for r,z gates only) ----------------
__global__ void k_btot(const float* __restrict__ bih, const float* __restrict__ bhh,
                       float* __restrict__ btot) {
  int i = blockIdx.x * 256 + threadIdx.x;
  if (i < GG) btot[i] = bih[i] + (i < 512 ? bhh[i] : 0.f);
}

// ---------------- phase 1: xg, per-tile uint2 records (proven R7-R16) -------
// D[gate-unit][batch]: A = W_ih rows (in regs), B = x (from LDS).
// Record: idx = ((tl*16 + mt)*48 + ut)*64 + lane; uint2 = packed bf16 of the
// 4 pre-acts for units ut*16 + quad*4 + {0..3}, batch row mt*16 + cu.
__global__ __attribute__((amdgpu_flat_work_group_size(512, 512), amdgpu_waves_per_eu(2, 2)))
void k_xg(const float* __restrict__ x,
    const float* __restrict__ Wih, const float* __restrict__ btot,
    unsigned short* __restrict__ xg, int t0)
{
  __shared__ unsigned short xlds[BB * II];   // 64KB, swizzled bf16 of x[:, t, :]
  const int tid = threadIdx.x;
  const int tl = blockIdx.x;
  const int tg = t0 + tl;
  const int w = tid >> 6, lane = tid & 63, cu = lane & 15, quad = lane >> 4;

  for (int i = 0; i < 16; ++i) {
    int cid = tid + i * 512;          // 8192 16B-chunks (256 rows x 32)
    int row = cid >> 5, c16 = cid & 31;
    const float4 v = *(const float4*)(x + (size_t)row * TT * II + (size_t)tg * II + c16 * 4);
    unsigned lo = f2bf(v.x) | (f2bf(v.y) << 16);
    unsigned hi = f2bf(v.z) | (f2bf(v.w) << 16);
    int byt = (row * 256 + c16 * 8) ^ ((row & 7) << 4);
    *(uint2*)((char*)xlds + byt) = make_uint2(lo, hi);
  }

  uint4 WA[3][2][4];
  float bias[3][2][4];
  #pragma unroll
  for (int pp = 0; pp < 3; ++pp)
    #pragma unroll
    for (int t2 = 0; t2 < 2; ++t2) {
      int ut = w * 6 + pp * 2 + t2;
      int grow = ut * 16 + cu;
      const float4* wr = (const float4*)(Wih + (size_t)grow * II);
      #pragma unroll
      for (int kk = 0; kk < 4; ++kk) {
        float4 lo = wr[kk * 8 + quad * 2];
        float4 hi = wr[kk * 8 + quad * 2 + 1];
        uint4 pk;
        pk.x = f2bf(lo.x) | (f2bf(lo.y) << 16);
        pk.y = f2bf(lo.z) | (f2bf(lo.w) << 16);
        pk.z = f2bf(hi.x) | (f2bf(hi.y) << 16);
        pk.w = f2bf(hi.z) | (f2bf(hi.w) << 16);
        WA[pp][t2][kk] = pk;
      }
      #pragma unroll
      for (int j = 0; j < 4; ++j)
        bias[pp][t2][j] = btot[ut * 16 + quad * 4 + j];
    }
  __syncthreads();

  #pragma unroll 1
  for (int mt = 0; mt < 16; ++mt) {
    short8 bf[4];
    int brow = mt * 16 + cu;
    #pragma unroll
    for (int kk = 0; kk < 4; ++kk) {
      int byt = (brow * 256 + kk * 64 + quad * 16) ^ ((cu & 7) << 4);
      bf[kk] = *(const short8*)((const char*)xlds + byt);
    }
    f32x4 acc[3][2];
    #pragma unroll
    for (int pp = 0; pp < 3; ++pp) {
      acc[pp][0] = (f32x4){0.f, 0.f, 0.f, 0.f};
      acc[pp][1] = (f32x4){0.f, 0.f, 0.f, 0.f};
    }
    #pragma unroll
    for (int kk = 0; kk < 4; ++kk)
      #pragma unroll
      for (int pp = 0; pp < 3; ++pp)
        #pragma unroll
        for (int t2 = 0; t2 < 2; ++t2)
          acc[pp][t2] = __builtin_amdgcn_mfma_f32_16x16x32_bf16(
              __builtin_bit_cast(short8, WA[pp][t2][kk]), bf[kk], acc[pp][t2], 0, 0, 0);
    #pragma unroll
    for (int pp = 0; pp < 3; ++pp)
      #pragma unroll
      for (int t2 = 0; t2 < 2; ++t2) {
        int ut = w * 6 + pp * 2 + t2;
        unsigned p0 = cvtpk_bf16(acc[pp][t2][0] + bias[pp][t2][0],
                                 acc[pp][t2][1] + bias[pp][t2][1]);
        unsigned p1 = cvtpk_bf16(acc[pp][t2][2] + bias[pp][t2][2],
                                 acc[pp][t2][3] + bias[pp][t2][3]);
        size_t rec = ((size_t)(tl * 16 + mt) * 48 + ut) * 64 + lane;
        ((uint2*)xg)[rec] = make_uint2(p0, p1);
      }
  }
}

// ---------------- phase 2: sequential scan (R16 verbatim) -------------------
// 16 waves x 16 units; W kk 0..6 in regs (VGPR+AGPR unified, 128/wave budget
// at 4 waves/SIMD), kk 7 in wlds; h double-buffered in hbuf (padded to 64KB:
// 1 WG/CU); full-row XOR bank swizzle. This is the measured structural floor:
// ~176 ds_read_b128/CU/step (h broadcast 128 + wlds 48) ~ 2900cy on the LDS
// pipe; MFMA (466cy) and gate VALU (~1000cy) hide beneath it; 3540cy/step.
__global__ __launch_bounds__(1024, 4) void k_scan(const float* __restrict__ Whh,
    const float* __restrict__ bhh, const float* __restrict__ alpha,
    const unsigned short* __restrict__ xg, float* __restrict__ hlast, int t0)
{
  __shared__ unsigned short hbuf[2][16384];     // 64KB; first 8KB of each half used
  __shared__ uint4 wlds[16][3][64];             // 48KB: W_hh kk=7 fragments
  const int tid = threadIdx.x, wv = tid >> 6, lane = tid & 63;
  const int cu = lane & 15, quad = lane >> 4;
  const int wg = blockIdx.x;

  // --- W_hh -> bf16 A-fragments: kk 0..6 regs, kk 7 LDS
  uint4 Wf[3][7];
  #pragma unroll
  for (int g = 0; g < 3; ++g) {
    int grow = g * 256 + wv * 16 + cu;
    const float4* wr = (const float4*)(Whh + (size_t)grow * HH);
    #pragma unroll
    for (int kk = 0; kk < 8; ++kk) {
      float4 lo = wr[kk * 8 + quad * 2];
      float4 hi = wr[kk * 8 + quad * 2 + 1];
      uint4 pk;
      pk.x = cvtpk_bf16(lo.x, lo.y);
      pk.y = cvtpk_bf16(lo.z, lo.w);
      pk.z = cvtpk_bf16(hi.x, hi.y);
      pk.w = cvtpk_bf16(hi.z, hi.w);
      if (kk < 7) Wf[g][kk] = pk;
      else        wlds[wv][g][lane] = pk;
    }
  }
  // per-lane unit constants (4 output units u0..u0+3), packed bf16
  const int u0 = wv * 16 + quad * 4;
  unsigned asigp[2], bhp[2];
  asigp[0] = cvtpk_bf16(sigm(alpha[u0]),     sigm(alpha[u0 + 1]));
  asigp[1] = cvtpk_bf16(sigm(alpha[u0 + 2]), sigm(alpha[u0 + 3]));
  bhp[0] = f2bf(bhh[512 + u0])     | (f2bf(bhh[512 + u0 + 1]) << 16);
  bhp[1] = f2bf(bhh[512 + u0 + 2]) | (f2bf(bhh[512 + u0 + 3]) << 16);

  // --- h init into LDS buf0 (full-row swizzle: bits (m&7)<<4 and (m>>3)<<6)
  for (int i = 0; i < 4; ++i) {
    int idx = tid * 4 + i;            // 4096 = 16 rows x 256 units
    int m = idx >> 8, u = idx & 255;
    float hv = (t0 == 0) ? 0.f : hlast[((size_t)wg * 16 + m) * 256 + u];
    int byt = (m * 512 + u * 2) ^ ((m & 7) << 4) ^ ((m >> 3) << 6);
    *(unsigned short*)((char*)hbuf[0] + byt) = (unsigned short)f2bf(hv);
  }
  __syncthreads();

  // --- LDS addresses (full-row XOR swizzle; buffer bit toggled by ^32768)
  const unsigned swz = (unsigned)(((cu & 7) << 4) ^ ((cu >> 3) << 6));
  const unsigned vb  = (unsigned)((cu * 512 + quad * 16)) ^ swz;
  const unsigned whp = (unsigned)((cu * 512 + wv * 32 + quad * 8)) ^ swz;

  // xg records: uint2 at ((t*16+wg)*48 + g*16 + wv)*64 + lane
  const uint2* xq = (const uint2*)xg + ((size_t)wg * 48 + wv) * 64 + lane;
  uint2 qn0 = xq[0], qn1 = xq[1024], qn2 = xq[2048];

  unsigned bufb = 0;
  const char* hbase = (const char*)hbuf;

  for (int tl = 0; tl < TCH; ++tl) {
    const char* hs = hbase + bufb;
    // ---- acc init: r,z from records; n = b_hh_n broadcast along batch
    f32x4 acc[3];
    acc[0][0]=bflo(qn0.x); acc[0][1]=bfhi(qn0.x); acc[0][2]=bflo(qn0.y); acc[0][3]=bfhi(qn0.y);
    acc[1][0]=bflo(qn1.x); acc[1][1]=bfhi(qn1.x); acc[1][2]=bflo(qn1.y); acc[1][3]=bfhi(qn1.y);
    acc[2][0]=bflo(bhp[0]); acc[2][1]=bfhi(bhp[0]);
    acc[2][2]=bflo(bhp[1]); acc[2][3]=bfhi(bhp[1]);
    uint2 q2c = qn2;                  // n-gate xg, unpacked at gate time
    // prefetch t+1 (3 uint2; hidden under the MFMA phase)
    if (tl < TCH - 1) xq += 49152;
    qn0 = xq[0]; qn1 = xq[1024]; qn2 = xq[2048];
    // h_prev for this lane's 4 output units
    uint2 hpq = *(const uint2*)(hs + whp);

    // ---- pre-acts += W_hh @ h^T : 24 intrinsic MFMAs
    #pragma unroll
    for (int kk = 0; kk < 7; ++kk) {
      short8 bfh = *(const short8*)(hs + (vb ^ (unsigned)(kk * 64)));
      #pragma unroll
      for (int g = 0; g < 3; ++g)
        acc[g] = __builtin_amdgcn_mfma_f32_16x16x32_bf16(
            __builtin_bit_cast(short8, Wf[g][kk]), bfh, acc[g], 0, 0, 0);
    }
    {
      short8 bfh = *(const short8*)(hs + (vb ^ (unsigned)(7 * 64)));
      #pragma unroll
      for (int g = 0; g < 3; ++g) {
        short8 wf = __builtin_bit_cast(short8, wlds[wv][g][lane]);
        acc[g] = __builtin_amdgcn_mfma_f32_16x16x32_bf16(wf, bfh, acc[g], 0, 0, 0);
      }
    }

    // ---- gates: h' = h + a * sigm(-pre_z) * (tanh(xgn + sigm(pre_r)*pre_n) - h)
    float hpv[4] = {bflo(hpq.x), bfhi(hpq.x), bflo(hpq.y), bfhi(hpq.y)};
    float xgn[4] = {bflo(q2c.x), bfhi(q2c.x), bflo(q2c.y), bfhi(q2c.y)};
    float av[4]  = {bflo(asigp[0]), bfhi(asigp[0]), bflo(asigp[1]), bfhi(asigp[1])};
    float ho[4];
    #pragma unroll
    for (int j = 0; j < 4; ++j) {
      float rr = sigm(acc[0][j]);                        // r-gate
      float ss = sigm(-acc[1][j]);                       // 1 - z
      float v  = fmaf(rr, acc[2][j], xgn[j]);
      float nn = 1.f - 2.f * __builtin_amdgcn_rcpf(
                     1.f + __builtin_amdgcn_exp2f(2.88539008177793f * v));
      ho[j] = fmaf(av[j] * ss, nn - hpv[j], hpv[j]);
    }
    unsigned p0 = cvtpk_bf16(ho[0], ho[1]);
    unsigned p1 = cvtpk_bf16(ho[2], ho[3]);
    *(uint2*)((char*)hbase + (bufb ^ 32768u) + whp) = make_uint2(p0, p1);
    if (tl == TCH - 1) {
      #pragma unroll
      for (int j = 0; j < 4; ++j)
        hlast[((size_t)wg * 16 + cu) * 256 + u0 + j] = ho[j];
    }
    __syncthreads();
    bufb ^= 32768u;
  }
}

// ---------------- phase 3: out = sigmoid(h_last @ fc_w^T + fc_b) ------------
__global__ void k_out(const float* __restrict__ hlast, const float* __restrict__ fcw,
                      const float* __restrict__ fcb, float* __restrict__ out)
{
  int g = blockIdx.x * 256 + threadIdx.x;   // 16384 outputs
  int b = g >> 6, o = g & 63;
  const float* hr = hlast + (size_t)b * HH;
  const float* wr = fcw + (size_t)o * HH;
  float acc = fcb[o];
  for (int u = 0; u < HH; ++u) acc = fmaf(hr[u], wr[u], acc);
  out[g] = sigm(acc);
}

extern "C" void kernel_launch(void* const* d_in, const int* in_sizes, int n_in,
                              void* d_out, int out_size, void* d_ws, size_t ws_size,
                              hipStream_t stream)
{
  const float* x   = (const float*)d_in[0];
  const float* Wih = (const float*)d_in[1];
  const float* Whh = (const float*)d_in[2];
  const float* bih = (const float*)d_in[3];
  const float* bhh = (const float*)d_in[4];
  const float* alp = (const float*)d_in[5];
  const float* fcw = (const float*)d_in[6];
  const float* fcb = (const float*)d_in[7];
  float* out = (float*)d_out;

  const size_t XGB   = (size_t)TCH * 16 * 48 * 64 * 8;      // 100,663,296 B
  const size_t HLB   = (size_t)BB * HH * 4;                 // 262,144 B
  const size_t BTB   = (size_t)GG * 4;                      // 3,072 B
  if (ws_size < XGB + HLB + BTB) return;                    // ~96.3+ MB scratch

  unsigned short* xg = (unsigned short*)d_ws;
  float* hlast = (float*)((char*)d_ws + XGB);
  float* btot  = (float*)((char*)d_ws + XGB + HLB);

  k_btot<<<3, 256, 0, stream>>>(bih, bhh, btot);
  for (int c = 0; c < NCH; ++c) {
    k_xg  <<<TCH, 512, 0, stream>>>(x, Wih, btot, xg, c * TCH);
    k_scan<<<16, 1024, 0, stream>>>(Whh, bhh, alp, xg, hlast, c * TCH);
  }
  k_out<<<64, 256, 0, stream>>>(hlast, fcw, fcb, out);
}